// Round 17
// baseline (158.785 us; speedup 1.0000x reference)
//
#include <hip/hip_runtime.h>
#include <hip/hip_bf16.h>
#include <cstdint>
#include <cstddef>

// Problem constants
#define BDIM   32768
#define KDIM   2048
#define NDIM   128
#define VHEADS 20
#define PDIM   6
#define RLORA  10

#define BM      32
#define BK      64
#define NCHUNK  (KDIM / BK)                 // 32
#define OUT_ELEMS   (BDIM * VHEADS * PDIM)  // 3932160
#define WS_W_BYTES  (KDIM * NDIM * 2)       // 524288

typedef __attribute__((ext_vector_type(8))) __bf16 bf16x8;
typedef __attribute__((ext_vector_type(4))) float f32x4;
typedef __attribute__((ext_vector_type(2))) float f32x2;
typedef __attribute__((ext_vector_type(4))) unsigned int u32x4;

union FragU { bf16x8 b; u32x4 u; };

__device__ __forceinline__ unsigned int cvt_pk_bf16(float lo, float hi) {
  unsigned int r;
  asm("v_cvt_pk_bf16_f32 %0, %1, %2" : "=v"(r) : "v"(lo), "v"(hi));
  return r;
}

__device__ __forceinline__ void gload_lds16(const void* g, void* l) {
  __builtin_amdgcn_global_load_lds(
      (const __attribute__((address_space(1))) void*)(g),
      (__attribute__((address_space(3))) void*)(l), 16, 0, 0);
}

__device__ __forceinline__ float fast_tanh(float x) {
  float ax = fabsf(x);
  float e  = __expf(-2.0f * ax);
  float t  = __fdividef(1.0f - e, 1.0f + e);
  return copysignf(t, x);
}

#define SBAR() __builtin_amdgcn_sched_barrier(0)
// Unmovable 16B global load with literal offset (13-bit signed: -4096..4095).
#define GL16(dst, addr, OFFSTR) \
  asm volatile("global_load_dwordx4 %0, %1, off offset:" OFFSTR \
               : "=v"(dst) : "v"(addr))

// ---------------------------------------------------------------------------
// k0: pack We1 f32[2048][128] -> bf16 in B-FRAGMENT-MAJOR order:
//   n = nt*16 + (lane&15), k = c*64 + ks*32 + (lane>>4)*8 + j.
//   Chunk c = 16 KB at c*16384; fragment (nt,ks) at (nt*2+ks)*1024 + lane*16.
// Also M = lora_A @ lora_B ([2][120]).
// ---------------------------------------------------------------------------
__global__ __launch_bounds__(256)
void k0_pack(const float* __restrict__ We1,
             const float* __restrict__ lA,
             const float* __restrict__ lB,
             unsigned short* __restrict__ wsw,
             float* __restrict__ wsM) {
  if (blockIdx.x == 128) {
    int t = threadIdx.x;
    if (t < 2 * VHEADS * PDIM) {
      int d  = t / (VHEADS * PDIM);
      int vp = t - d * (VHEADS * PDIM);
      float s = 0.f;
#pragma unroll
      for (int r = 0; r < RLORA; ++r)
        s = fmaf(lA[d * RLORA + r], lB[r * (VHEADS * PDIM) + vp], s);
      wsM[t] = s;  // layout [d][vp]
    }
    return;
  }
  int t    = blockIdx.x * 256 + threadIdx.x;  // 0..32767
  int lane = t & 63;
  int blk  = t >> 6;                          // 0..511
  int ks   = blk & 1;
  int nt   = (blk >> 1) & 7;
  int c    = blk >> 4;
  int n    = nt * 16 + (lane & 15);
  int kb   = c * 64 + ks * 32 + (lane >> 4) * 8;

  unsigned int u[4];
#pragma unroll
  for (int q = 0; q < 4; ++q) {
    float f0 = We1[(size_t)(kb + 2 * q + 0) * NDIM + n];
    float f1 = We1[(size_t)(kb + 2 * q + 1) * NDIM + n];
    __hip_bfloat16 h0 = __float2bfloat16(f0);
    __hip_bfloat16 h1 = __float2bfloat16(f1);
    u[q] = (unsigned int)*reinterpret_cast<unsigned short*>(&h0) |
           ((unsigned int)*reinterpret_cast<unsigned short*>(&h1) << 16);
  }
  *reinterpret_cast<u32x4*>(wsw + (size_t)t * 8) = u32x4{u[0], u[1], u[2], u[3]};
}

// ---------------------------------------------------------------------------
// k1: fused encoder + heads.  ZERO-BARRIER WAVE-PRIVATE pipeline.
//   1024 blocks x 256 thr (4 waves: wr = wv&1 row-group x16, wc = wv>>1
//   col-half x64).  Each wave fully independent in the main loop:
//   A: its own 16 rows staged via global_load_lds into its private 4 KB
//      regions of static parity buffers A0_/A1_ (source granule XOR-swz
//      s^(row&7), linear dest).  wc-duplicate A reads hit L1/L2.
//   B: 8 asm global_load_dwordx4/chunk from the L2-resident pack (single
//      reg set; MFMA latches operands at issue so reuse is WAR-safe).
//   Per chunk: LOADB(c) -> STAGE_A(c+1) -> s_waitcnt vmcnt(4) -> COMPUTE.
//   NO s_barrier in the loop; waves free-run (no convoy).  16 waves/CU.
//   Epilogue: 2 syncthreads total (cross-wc z combine), fused heads.
// ---------------------------------------------------------------------------
__global__ __launch_bounds__(256, 4)
void k1_fused(const float* __restrict__ x,
              const unsigned short* __restrict__ wp,
              const float* __restrict__ be1,
              const float* __restrict__ We2,
              const float* __restrict__ be2,
              const float* __restrict__ W1,
              const float* __restrict__ b1,
              const float* __restrict__ W2,
              const float* __restrict__ b2,
              const float* __restrict__ M,
              float* __restrict__ out,
              float* __restrict__ zout) {
  __shared__ char A0_[16384] __attribute__((aligned(16)));  // 4 waves x 4 KB
  __shared__ char A1_[16384] __attribute__((aligned(16)));
  __shared__ float zpart2[32][2][2];   // [row][col-half][d]
  __shared__ float zsh[32][2];

  const int tid  = threadIdx.x;        // 0..255
  const int lane = tid & 63;
  const int wv   = tid >> 6;           // 0..3
  const int wr   = wv & 1;             // row-group (x16)
  const int wc   = wv >> 1;            // col-half (x64)
  const int l15  = lane & 15;
  const int kgrp = lane >> 4;          // 0..3
  const int blk  = blockIdx.x;

  // B: this wave's 8 fragments of chunk c at wp + wc*8192 + c*16384 + lane*16.
  // Base biased +4096 so literal offsets span -4096..+3072.
  const char* bwave = (const char*)wp + wc * 8192 + lane * 16 + 4096;

  f32x4 acc[4];
#pragma unroll
  for (int i = 0; i < 4; ++i) acc[i] = f32x4{0.f, 0.f, 0.f, 0.f};

  auto STAGE_A = [&](char* Ad, int c) {
    // instr q stages local rows q*4 + (lane>>4); dest = wv*4096 + q*1024
    // + lane*16 (linear); source granule = (l15)^(lr&7).
#pragma unroll
    for (int q = 0; q < 4; ++q) {
      int lr = q * 4 + (lane >> 4);
      const float* asrc = x + (size_t)(blk * BM + wr * 16 + lr) * KDIM + c * BK
                          + ((l15 ^ (lr & 7)) << 2);
      gload_lds16(asrc, Ad + wv * 4096 + q * 1024);
    }
  };

  FragU bf[8];
  auto LOADB = [&](int c) {
    const char* p = bwave + (size_t)c * 16384;
    GL16(bf[0].u, p, "-4096");
    GL16(bf[1].u, p, "-3072");
    GL16(bf[2].u, p, "-2048");
    GL16(bf[3].u, p, "-1024");
    GL16(bf[4].u, p, "0");
    GL16(bf[5].u, p, "1024");
    GL16(bf[6].u, p, "2048");
    GL16(bf[7].u, p, "3072");
  };

  auto COMPUTE = [&](const char* Ad) {
    const char* abase = Ad + wv * 4096 + l15 * 256;
    const int rx = (l15 & 7) << 4;
    f32x4 A0 = *(const f32x4*)(abase + (((kgrp * 2 + 0) << 4) ^ rx));
    f32x4 A1 = *(const f32x4*)(abase + (((kgrp * 2 + 1) << 4) ^ rx));
    f32x4 A2 = *(const f32x4*)(abase + 128 + (((kgrp * 2 + 0) << 4) ^ rx));
    f32x4 A3 = *(const f32x4*)(abase + 128 + (((kgrp * 2 + 1) << 4) ^ rx));
    FragU a0, a1;
    a0.u = u32x4{cvt_pk_bf16(A0.x, A0.y), cvt_pk_bf16(A0.z, A0.w),
                 cvt_pk_bf16(A1.x, A1.y), cvt_pk_bf16(A1.z, A1.w)};
    a1.u = u32x4{cvt_pk_bf16(A2.x, A2.y), cvt_pk_bf16(A2.z, A2.w),
                 cvt_pk_bf16(A3.x, A3.y), cvt_pk_bf16(A3.z, A3.w)};
    acc[0] = __builtin_amdgcn_mfma_f32_16x16x32_bf16(a0.b, bf[0].b, acc[0], 0, 0, 0);
    acc[0] = __builtin_amdgcn_mfma_f32_16x16x32_bf16(a1.b, bf[1].b, acc[0], 0, 0, 0);
    acc[1] = __builtin_amdgcn_mfma_f32_16x16x32_bf16(a0.b, bf[2].b, acc[1], 0, 0, 0);
    acc[1] = __builtin_amdgcn_mfma_f32_16x16x32_bf16(a1.b, bf[3].b, acc[1], 0, 0, 0);
    acc[2] = __builtin_amdgcn_mfma_f32_16x16x32_bf16(a0.b, bf[4].b, acc[2], 0, 0, 0);
    acc[2] = __builtin_amdgcn_mfma_f32_16x16x32_bf16(a1.b, bf[5].b, acc[2], 0, 0, 0);
    acc[3] = __builtin_amdgcn_mfma_f32_16x16x32_bf16(a0.b, bf[6].b, acc[3], 0, 0, 0);
    acc[3] = __builtin_amdgcn_mfma_f32_16x16x32_bf16(a1.b, bf[7].b, acc[3], 0, 0, 0);
  };

  // prologue: A chunk 0 in flight (4 DMA)
  STAGE_A(A0_, 0);

#pragma unroll 1
  for (int cc = 0; cc < NCHUNK / 2; ++cc) {     // chunks 2cc, 2cc+1
    LOADB(2 * cc);                               // +8  -> 12 outstanding
    STAGE_A(A1_, 2 * cc + 1);                    // +4  -> 16
    asm volatile("s_waitcnt vmcnt(4)" ::: "memory");  // A(2cc)+B(2cc) landed
    SBAR();
    COMPUTE(A0_);
    SBAR();
    LOADB(2 * cc + 1);                           // +8  -> 12
    if (cc + 1 < NCHUNK / 2) STAGE_A(A0_, 2 * cc + 2);  // +4 -> 16
    if (cc + 1 < NCHUNK / 2) {
      asm volatile("s_waitcnt vmcnt(4)" ::: "memory");
    } else {
      asm volatile("s_waitcnt vmcnt(0)" ::: "memory");
    }
    SBAR();
    COMPUTE(A1_);
    SBAR();
  }

  // ---- epilogue: +be1, relu, @We2 partials (this wave's 64 cols)
  float part[4][2];
#pragma unroll
  for (int j = 0; j < 4; ++j) { part[j][0] = 0.f; part[j][1] = 0.f; }
#pragma unroll
  for (int nt = 0; nt < 4; ++nt) {
    int col = (wc * 4 + nt) * 16 + l15;
    float bb = be1[col];
    float w0 = We2[col * 2 + 0];
    float w1 = We2[col * 2 + 1];
#pragma unroll
    for (int j = 0; j < 4; ++j) {
      float h = acc[nt][j] + bb;
      h = h > 0.f ? h : 0.f;
      part[j][0] = fmaf(h, w0, part[j][0]);
      part[j][1] = fmaf(h, w1, part[j][1]);
    }
  }
#pragma unroll
  for (int m = 1; m < 16; m <<= 1) {
#pragma unroll
    for (int j = 0; j < 4; ++j) {
      part[j][0] += __shfl_xor(part[j][0], m, 64);
      part[j][1] += __shfl_xor(part[j][1], m, 64);
    }
  }
  if (l15 == 0) {
#pragma unroll
    for (int j = 0; j < 4; ++j) {
      int rl = wr * 16 + kgrp * 4 + j;   // C row = (lane>>4)*4 + reg
      zpart2[rl][wc][0] = part[j][0];
      zpart2[rl][wc][1] = part[j][1];
    }
  }
  __syncthreads();
  if (tid < BM) {
    float s0 = zpart2[tid][0][0] + zpart2[tid][1][0] + be2[0];
    float s1 = zpart2[tid][0][1] + zpart2[tid][1][1] + be2[1];
    zsh[tid][0] = s0;
    zsh[tid][1] = s1;
    f32x2 zz = {s0, s1};
    *(f32x2*)(zout + (size_t)(blk * BM + tid) * 2) = zz;
  }
  __syncthreads();

  // ---- heads: row = tid&31, slot = tid>>5 (8 slots; 0-3 do 3 heads, 4-7 do 2)
  const int srow = tid & 31;
  const int slot = tid >> 5;
  float z0 = zsh[srow][0];
  float z1 = zsh[srow][1];
  float* orow = out + (size_t)(blk * BM + srow) * (VHEADS * PDIM);

  auto head = [&](int v) {
    const float* w1a = W1 + (size_t)(v * 2 + 0) * NDIM;
    const float* w1b = W1 + (size_t)(v * 2 + 1) * NDIM;
    const float* bb1 = b1 + (size_t)v * NDIM;
    const float* w2  = W2 + (size_t)v * NDIM * PDIM;

    float p[6] = {0.f, 0.f, 0.f, 0.f, 0.f, 0.f};
#pragma unroll 4
    for (int h = 0; h < NDIM; ++h) {
      float hv = fmaf(z0, w1a[h], fmaf(z1, w1b[h], bb1[h]));
      hv = hv > 0.f ? hv : 0.f;
#pragma unroll
      for (int j = 0; j < 6; ++j) p[j] = fmaf(hv, w2[h * 6 + j], p[j]);
    }
    float o[6];
#pragma unroll
    for (int j = 0; j < 6; ++j) {
      float t1 = fast_tanh(p[j] + b2[v * PDIM + j]);
      float lo = fmaf(z0, M[v * PDIM + j], z1 * M[VHEADS * PDIM + v * PDIM + j]);
      o[j] = fast_tanh(fmaf(0.15f, lo, t1));
    }
    float* op = orow + v * PDIM;
    f32x2 o01 = {o[0], o[1]};
    f32x2 o23 = {o[2], o[3]};
    f32x2 o45 = {o[4], o[5]};
    __builtin_nontemporal_store(o01, (f32x2*)(op + 0));
    __builtin_nontemporal_store(o23, (f32x2*)(op + 2));
    __builtin_nontemporal_store(o45, (f32x2*)(op + 4));
  };

  head(slot);
  head(slot + 8);
  if (slot < 4) head(slot + 16);
}

// ---------------------------------------------------------------------------
extern "C" void kernel_launch(void* const* d_in, const int* in_sizes, int n_in,
                              void* d_out, int out_size, void* d_ws, size_t ws_size,
                              hipStream_t stream) {
  const float* x   = (const float*)d_in[0];
  const float* We1 = (const float*)d_in[1];
  const float* be1 = (const float*)d_in[2];
  const float* We2 = (const float*)d_in[3];
  const float* be2 = (const float*)d_in[4];
  const float* W1  = (const float*)d_in[5];
  const float* b1  = (const float*)d_in[6];
  const float* W2  = (const float*)d_in[7];
  const float* b2  = (const float*)d_in[8];
  const float* lA  = (const float*)d_in[9];
  const float* lB  = (const float*)d_in[10];

  float* out  = (float*)d_out;
  float* zout = out + OUT_ELEMS;                       // second tuple output
  unsigned short* wsw = (unsigned short*)d_ws;         // 512 KB bf16 W pack
  float* wsM = (float*)((char*)d_ws + WS_W_BYTES);     // 240 floats

  hipLaunchKernelGGL(k0_pack, dim3(129), dim3(256), 0, stream,
                     We1, lA, lB, wsw, wsM);
  hipLaunchKernelGGL(k1_fused, dim3(BDIM / BM), dim3(256), 0, stream,
                     x, wsw, be1, We2, be2, W1, b1, W2, b2, wsM, out, zout);
}

// Round 18
// 147.938 us; speedup vs baseline: 1.0733x; 1.0733x over previous
//
#include <hip/hip_runtime.h>
#include <hip/hip_bf16.h>
#include <cstdint>
#include <cstddef>

// Problem constants
#define BDIM   32768
#define KDIM   2048
#define NDIM   128
#define VHEADS 20
#define PDIM   6
#define RLORA  10

#define BM      128
#define BK      64
#define NCHUNK  (KDIM / BK)                 // 32
#define OUT_ELEMS   (BDIM * VHEADS * PDIM)  // 3932160
#define WS_W_BYTES  (KDIM * NDIM * 2)       // 524288

typedef __attribute__((ext_vector_type(8))) __bf16 bf16x8;
typedef __attribute__((ext_vector_type(4))) float f32x4;
typedef __attribute__((ext_vector_type(2))) float f32x2;
typedef __attribute__((ext_vector_type(4))) unsigned int u32x4;

union FragU { bf16x8 b; u32x4 u; };

__device__ __forceinline__ unsigned int cvt_pk_bf16(float lo, float hi) {
  unsigned int r;
  asm("v_cvt_pk_bf16_f32 %0, %1, %2" : "=v"(r) : "v"(lo), "v"(hi));
  return r;
}

__device__ __forceinline__ void gload_lds16(const void* g, void* l) {
  __builtin_amdgcn_global_load_lds(
      (const __attribute__((address_space(1))) void*)(g),
      (__attribute__((address_space(3))) void*)(l), 16, 0, 0);
}

__device__ __forceinline__ float fast_tanh(float x) {
  float ax = fabsf(x);
  float e  = __expf(-2.0f * ax);
  float t  = __fdividef(1.0f - e, 1.0f + e);
  return copysignf(t, x);
}

#define SBAR() __builtin_amdgcn_sched_barrier(0)

// ---------------------------------------------------------------------------
// k0: pack We1 f32[2048][128] -> bf16 in B-FRAGMENT-MAJOR order:
//   n = nt*16 + (lane&15), k = c*64 + ks*32 + (lane>>4)*8 + j.
//   Chunk c = 16 KB at c*16384; fragment (nt,ks) at (nt*2+ks)*1024 + lane*16.
// Also M = lora_A @ lora_B ([2][120]).
// ---------------------------------------------------------------------------
__global__ __launch_bounds__(256)
void k0_pack(const float* __restrict__ We1,
             const float* __restrict__ lA,
             const float* __restrict__ lB,
             unsigned short* __restrict__ wsw,
             float* __restrict__ wsM) {
  if (blockIdx.x == 128) {
    int t = threadIdx.x;
    if (t < 2 * VHEADS * PDIM) {
      int d  = t / (VHEADS * PDIM);
      int vp = t - d * (VHEADS * PDIM);
      float s = 0.f;
#pragma unroll
      for (int r = 0; r < RLORA; ++r)
        s = fmaf(lA[d * RLORA + r], lB[r * (VHEADS * PDIM) + vp], s);
      wsM[t] = s;  // layout [d][vp]
    }
    return;
  }
  int t    = blockIdx.x * 256 + threadIdx.x;  // 0..32767
  int lane = t & 63;
  int blk  = t >> 6;                          // 0..511
  int ks   = blk & 1;
  int nt   = (blk >> 1) & 7;
  int c    = blk >> 4;
  int n    = nt * 16 + (lane & 15);
  int kb   = c * 64 + ks * 32 + (lane >> 4) * 8;

  unsigned int u[4];
#pragma unroll
  for (int q = 0; q < 4; ++q) {
    float f0 = We1[(size_t)(kb + 2 * q + 0) * NDIM + n];
    float f1 = We1[(size_t)(kb + 2 * q + 1) * NDIM + n];
    __hip_bfloat16 h0 = __float2bfloat16(f0);
    __hip_bfloat16 h1 = __float2bfloat16(f1);
    u[q] = (unsigned int)*reinterpret_cast<unsigned short*>(&h0) |
           ((unsigned int)*reinterpret_cast<unsigned short*>(&h1) << 16);
  }
  *reinterpret_cast<u32x4*>(wsw + (size_t)t * 8) = u32x4{u[0], u[1], u[2], u[3]};
}

// ---------------------------------------------------------------------------
// k1: fused encoder + heads.  R14 cadence at BM=128 (B restream HALVED).
//   256 blocks x 1024 thr (16 waves: wr = wv&7 row-group x16, wc = wv>>3
//   col-half x64).  Per chunk: A = f32 [128][64] (32 KB) via global_load_lds
//   into STATIC double-buffers A0_/A1_ (linear dest, source granule
//   XOR-swizzled s^(row&7)); B = 16 KB fragment pack, SINGLE-buffered
//   (staged one phase ahead -- ample cover for L2-resident B).
//   3 loads/thread/chunk; steady-state s_waitcnt vmcnt(2) (current chunk's
//   A+B landed, next A's 2 stay in flight across both raw s_barriers --
//   never drain to 0 in the loop).  LDS ~85 KB, 1 block/CU, 16 waves/CU.
//   Combined traffic 536 -> 402 MB vs BM=64.
//   Epilogue: be1/relu/We2 partials, shfl-reduce, cross-half combine -> z;
//   fused heads (8 slots x 128 rows).
// ---------------------------------------------------------------------------
__global__ __launch_bounds__(1024, 4)
void k1_fused(const float* __restrict__ x,
              const unsigned short* __restrict__ wp,
              const float* __restrict__ be1,
              const float* __restrict__ We2,
              const float* __restrict__ be2,
              const float* __restrict__ W1,
              const float* __restrict__ b1,
              const float* __restrict__ W2,
              const float* __restrict__ b2,
              const float* __restrict__ M,
              float* __restrict__ out,
              float* __restrict__ zout) {
  __shared__ char A0_[32768] __attribute__((aligned(16)));
  __shared__ char A1_[32768] __attribute__((aligned(16)));
  __shared__ char B0_[16384] __attribute__((aligned(16)));
  __shared__ float zpart2[128][2][2];   // [row][col-half][d]
  __shared__ float zsh[128][2];

  const int tid  = threadIdx.x;        // 0..1023
  const int lane = tid & 63;
  const int wv   = tid >> 6;           // 0..15
  const int wr   = wv & 7;             // row-group (x16)
  const int wc   = wv >> 3;            // col-half (x64)
  const int l15  = lane & 15;
  const int kgrp = lane >> 4;          // 0..3
  const int blk  = blockIdx.x;

  f32x4 acc[4];
#pragma unroll
  for (int i = 0; i < 4; ++i) acc[i] = f32x4{0.f, 0.f, 0.f, 0.f};

  auto STAGE_A = [&](char* Ad, int c) {
    // slots s = tid, tid+1024: row = s>>4 (0..127), dest granule s&15,
    // source granule (s&15)^(row&7)
#pragma unroll
    for (int q = 0; q < 2; ++q) {
      int s = tid + q * 1024;
      int row = s >> 4;
      int g = (s & 15) ^ (row & 7);
      const float* asrc = x + (size_t)(blk * BM + row) * KDIM + c * BK + g * 4;
      gload_lds16(asrc, Ad + s * 16);
    }
  };
  auto STAGE_B = [&](int c) {
    gload_lds16((const char*)wp + (size_t)c * 16384 + tid * 16,
                B0_ + tid * 16);
  };

  auto COMPUTE = [&](const char* Ad) {
    const int row = wr * 16 + l15;
    const char* abase = Ad + row * 256;
    const int rx = (row & 7) << 4;
    f32x4 A0 = *(const f32x4*)(abase + (((kgrp * 2 + 0) << 4) ^ rx));
    f32x4 A1 = *(const f32x4*)(abase + (((kgrp * 2 + 1) << 4) ^ rx));
    f32x4 A2 = *(const f32x4*)(abase + 128 + (((kgrp * 2 + 0) << 4) ^ rx));
    f32x4 A3 = *(const f32x4*)(abase + 128 + (((kgrp * 2 + 1) << 4) ^ rx));
    FragU a0, a1;
    a0.u = u32x4{cvt_pk_bf16(A0.x, A0.y), cvt_pk_bf16(A0.z, A0.w),
                 cvt_pk_bf16(A1.x, A1.y), cvt_pk_bf16(A1.z, A1.w)};
    a1.u = u32x4{cvt_pk_bf16(A2.x, A2.y), cvt_pk_bf16(A2.z, A2.w),
                 cvt_pk_bf16(A3.x, A3.y), cvt_pk_bf16(A3.z, A3.w)};
    const char* bbase = B0_ + lane * 16;
#pragma unroll
    for (int nt = 0; nt < 4; ++nt) {
      FragU b0, b1;
      b0.u = *(const u32x4*)(bbase + ((wc * 4 + nt) * 2 + 0) * 1024);
      b1.u = *(const u32x4*)(bbase + ((wc * 4 + nt) * 2 + 1) * 1024);
      acc[nt] = __builtin_amdgcn_mfma_f32_16x16x32_bf16(a0.b, b0.b, acc[nt], 0, 0, 0);
      acc[nt] = __builtin_amdgcn_mfma_f32_16x16x32_bf16(a1.b, b1.b, acc[nt], 0, 0, 0);
    }
  };

  // prologue: B(0) + A(0) + A(1) in flight (5 loads/thread)
  STAGE_B(0);
  STAGE_A(A0_, 0);
  STAGE_A(A1_, 1);

#pragma unroll 1
  for (int cc = 0; cc < NCHUNK / 2; ++cc) {   // chunks 2cc, 2cc+1
    asm volatile("s_waitcnt vmcnt(2)" ::: "memory");   // A(2cc)+B(2cc) landed
    SBAR();
    __builtin_amdgcn_s_barrier();
    COMPUTE(A0_);
    __builtin_amdgcn_s_barrier();
    SBAR();
    STAGE_B(2 * cc + 1);                      // B one phase ahead (L2-hot)
    if (cc + 1 < NCHUNK / 2) STAGE_A(A0_, 2 * cc + 2);   // A two ahead
    if (cc + 1 < NCHUNK / 2) {
      asm volatile("s_waitcnt vmcnt(2)" ::: "memory");   // A+B(2cc+1) landed
    } else {
      asm volatile("s_waitcnt vmcnt(0)" ::: "memory");
    }
    SBAR();
    __builtin_amdgcn_s_barrier();
    COMPUTE(A1_);
    __builtin_amdgcn_s_barrier();
    SBAR();
    if (cc + 1 < NCHUNK / 2) {
      STAGE_B(2 * cc + 2);
      STAGE_A(A1_, 2 * cc + 3);
    }
  }

  // ---- epilogue: +be1, relu, @We2 partials (this wave's 64 cols)
  float part[4][2];
#pragma unroll
  for (int j = 0; j < 4; ++j) { part[j][0] = 0.f; part[j][1] = 0.f; }
#pragma unroll
  for (int nt = 0; nt < 4; ++nt) {
    int col = (wc * 4 + nt) * 16 + l15;
    float bb = be1[col];
    float w0 = We2[col * 2 + 0];
    float w1 = We2[col * 2 + 1];
#pragma unroll
    for (int j = 0; j < 4; ++j) {
      float h = acc[nt][j] + bb;
      h = h > 0.f ? h : 0.f;
      part[j][0] = fmaf(h, w0, part[j][0]);
      part[j][1] = fmaf(h, w1, part[j][1]);
    }
  }
#pragma unroll
  for (int m = 1; m < 16; m <<= 1) {
#pragma unroll
    for (int j = 0; j < 4; ++j) {
      part[j][0] += __shfl_xor(part[j][0], m, 64);
      part[j][1] += __shfl_xor(part[j][1], m, 64);
    }
  }
  if (l15 == 0) {
#pragma unroll
    for (int j = 0; j < 4; ++j) {
      int rl = wr * 16 + kgrp * 4 + j;   // C row = (lane>>4)*4 + reg
      zpart2[rl][wc][0] = part[j][0];
      zpart2[rl][wc][1] = part[j][1];
    }
  }
  __syncthreads();
  if (tid < BM) {
    float s0 = zpart2[tid][0][0] + zpart2[tid][1][0] + be2[0];
    float s1 = zpart2[tid][0][1] + zpart2[tid][1][1] + be2[1];
    zsh[tid][0] = s0;
    zsh[tid][1] = s1;
    f32x2 zz = {s0, s1};
    *(f32x2*)(zout + (size_t)(blk * BM + tid) * 2) = zz;
  }
  __syncthreads();

  // ---- heads: row = tid&127, slot = tid>>7 (8 slots; 0-3: 3 heads, 4-7: 2)
  const int srow = tid & 127;
  const int slot = tid >> 7;
  float z0 = zsh[srow][0];
  float z1 = zsh[srow][1];
  float* orow = out + (size_t)(blk * BM + srow) * (VHEADS * PDIM);

  auto head = [&](int v) {
    const float* w1a = W1 + (size_t)(v * 2 + 0) * NDIM;
    const float* w1b = W1 + (size_t)(v * 2 + 1) * NDIM;
    const float* bb1 = b1 + (size_t)v * NDIM;
    const float* w2  = W2 + (size_t)v * NDIM * PDIM;

    float p[6] = {0.f, 0.f, 0.f, 0.f, 0.f, 0.f};
#pragma unroll 4
    for (int h = 0; h < NDIM; ++h) {
      float hv = fmaf(z0, w1a[h], fmaf(z1, w1b[h], bb1[h]));
      hv = hv > 0.f ? hv : 0.f;
#pragma unroll
      for (int j = 0; j < 6; ++j) p[j] = fmaf(hv, w2[h * 6 + j], p[j]);
    }
    float o[6];
#pragma unroll
    for (int j = 0; j < 6; ++j) {
      float t1 = fast_tanh(p[j] + b2[v * PDIM + j]);
      float lo = fmaf(z0, M[v * PDIM + j], z1 * M[VHEADS * PDIM + v * PDIM + j]);
      o[j] = fast_tanh(fmaf(0.15f, lo, t1));
    }
    float* op = orow + v * PDIM;
    f32x2 o01 = {o[0], o[1]};
    f32x2 o23 = {o[2], o[3]};
    f32x2 o45 = {o[4], o[5]};
    __builtin_nontemporal_store(o01, (f32x2*)(op + 0));
    __builtin_nontemporal_store(o23, (f32x2*)(op + 2));
    __builtin_nontemporal_store(o45, (f32x2*)(op + 4));
  };

  head(slot);
  head(slot + 8);
  if (slot < 4) head(slot + 16);
}

// ---------------------------------------------------------------------------
extern "C" void kernel_launch(void* const* d_in, const int* in_sizes, int n_in,
                              void* d_out, int out_size, void* d_ws, size_t ws_size,
                              hipStream_t stream) {
  const float* x   = (const float*)d_in[0];
  const float* We1 = (const float*)d_in[1];
  const float* be1 = (const float*)d_in[2];
  const float* We2 = (const float*)d_in[3];
  const float* be2 = (const float*)d_in[4];
  const float* W1  = (const float*)d_in[5];
  const float* b1  = (const float*)d_in[6];
  const float* W2  = (const float*)d_in[7];
  const float* b2  = (const float*)d_in[8];
  const float* lA  = (const float*)d_in[9];
  const float* lB  = (const float*)d_in[10];

  float* out  = (float*)d_out;
  float* zout = out + OUT_ELEMS;                       // second tuple output
  unsigned short* wsw = (unsigned short*)d_ws;         // 512 KB bf16 W pack
  float* wsM = (float*)((char*)d_ws + WS_W_BYTES);     // 240 floats

  hipLaunchKernelGGL(k0_pack, dim3(129), dim3(256), 0, stream,
                     We1, lA, lB, wsw, wsM);
  hipLaunchKernelGGL(k1_fused, dim3(BDIM / BM), dim3(1024), 0, stream,
                     x, wsw, be1, We2, be2, W1, b1, W2, b2, wsM, out, zout);
}

// Round 19
// 113.293 us; speedup vs baseline: 1.4015x; 1.3058x over previous
//
#include <hip/hip_runtime.h>
#include <hip/hip_bf16.h>
#include <cstdint>
#include <cstddef>

// Problem constants
#define BDIM   32768
#define KDIM   2048
#define NDIM   128
#define VHEADS 20
#define PDIM   6
#define RLORA  10

#define BM      64
#define BK      64
#define NCHUNK  (KDIM / BK)                 // 32
#define OUT_ELEMS   (BDIM * VHEADS * PDIM)  // 3932160
#define WS_W_BYTES  (KDIM * NDIM * 2)       // 524288

typedef __attribute__((ext_vector_type(8))) __bf16 bf16x8;
typedef __attribute__((ext_vector_type(4))) float f32x4;
typedef __attribute__((ext_vector_type(2))) float f32x2;
typedef __attribute__((ext_vector_type(4))) unsigned int u32x4;

union FragU { bf16x8 b; u32x4 u; };

__device__ __forceinline__ unsigned int cvt_pk_bf16(float lo, float hi) {
  unsigned int r;
  asm("v_cvt_pk_bf16_f32 %0, %1, %2" : "=v"(r) : "v"(lo), "v"(hi));
  return r;
}

__device__ __forceinline__ void gload_lds16(const void* g, void* l) {
  __builtin_amdgcn_global_load_lds(
      (const __attribute__((address_space(1))) void*)(g),
      (__attribute__((address_space(3))) void*)(l), 16, 0, 0);
}

__device__ __forceinline__ float fast_tanh(float x) {
  float ax = fabsf(x);
  float e  = __expf(-2.0f * ax);
  float t  = __fdividef(1.0f - e, 1.0f + e);
  return copysignf(t, x);
}

#define SBAR() __builtin_amdgcn_sched_barrier(0)
// Unmovable 16B global load with literal offset (13-bit signed: -4096..4095).
#define GL16(dst, addr, OFFSTR) \
  asm volatile("global_load_dwordx4 %0, %1, off offset:" OFFSTR \
               : "=v"(dst) : "v"(addr))

// ---------------------------------------------------------------------------
// k0: pack We1 f32[2048][128] -> bf16 in B-FRAGMENT-MAJOR order:
//   n = nt*16 + (lane&15), k = c*64 + ks*32 + (lane>>4)*8 + j.
//   Chunk c = 16 KB at c*16384; fragment (nt,ks) at (nt*2+ks)*1024 + lane*16.
// Also M = lora_A @ lora_B ([2][120]).
// ---------------------------------------------------------------------------
__global__ __launch_bounds__(256)
void k0_pack(const float* __restrict__ We1,
             const float* __restrict__ lA,
             const float* __restrict__ lB,
             unsigned short* __restrict__ wsw,
             float* __restrict__ wsM) {
  if (blockIdx.x == 128) {
    int t = threadIdx.x;
    if (t < 2 * VHEADS * PDIM) {
      int d  = t / (VHEADS * PDIM);
      int vp = t - d * (VHEADS * PDIM);
      float s = 0.f;
#pragma unroll
      for (int r = 0; r < RLORA; ++r)
        s = fmaf(lA[d * RLORA + r], lB[r * (VHEADS * PDIM) + vp], s);
      wsM[t] = s;  // layout [d][vp]
    }
    return;
  }
  int t    = blockIdx.x * 256 + threadIdx.x;  // 0..32767
  int lane = t & 63;
  int blk  = t >> 6;                          // 0..511
  int ks   = blk & 1;
  int nt   = (blk >> 1) & 7;
  int c    = blk >> 4;
  int n    = nt * 16 + (lane & 15);
  int kb   = c * 64 + ks * 32 + (lane >> 4) * 8;

  unsigned int u[4];
#pragma unroll
  for (int q = 0; q < 4; ++q) {
    float f0 = We1[(size_t)(kb + 2 * q + 0) * NDIM + n];
    float f1 = We1[(size_t)(kb + 2 * q + 1) * NDIM + n];
    __hip_bfloat16 h0 = __float2bfloat16(f0);
    __hip_bfloat16 h1 = __float2bfloat16(f1);
    u[q] = (unsigned int)*reinterpret_cast<unsigned short*>(&h0) |
           ((unsigned int)*reinterpret_cast<unsigned short*>(&h1) << 16);
  }
  *reinterpret_cast<u32x4*>(wsw + (size_t)t * 8) = u32x4{u[0], u[1], u[2], u[3]};
}

// ---------------------------------------------------------------------------
// k1: fused encoder + heads.  QUAD-BUFFER A + REG-B + ONE BARRIER/PHASE.
//   512 blocks x 512 thr (8 waves: wr = wv&3 row-group x16, wc = wv>>2
//   col-half x64).  Phase c (chunk c):
//     s_waitcnt vmcnt(12) -> s_barrier -> COMPUTE(A[c%4], Breg[c%2])
//     -> LOADB(Breg[c%2], c+2) -> STAGE_A(A[(c+3)%4], c+3)
//   FIFO: at the wait, A(c) (3 phases old) and B(c) (2 phases old) have
//   exactly 12 newer loads (A(c+1),B(c+1),A(c+2)) -> vmcnt(12) keeps 3
//   A-chunks + 1 B-chunk in flight, issue spread each phase, never 0.
//   A: f32 [64][64] via global_load_lds into 4 STATIC 16 KB buffers
//      (linear dest, source granule XOR-swizzled s^(row&7)); WAR-safe at
//      3-phase spacing with one barrier/phase.
//   B: 8 asm global_load_dwordx4 from the L2-resident pack into named
//      dbuf reg sets bE/bO (base biased +4096 for 13-bit offsets).
//   LDS 67 KB -> 2 blocks/CU, 16 waves/CU.
//   Epilogue: be1/relu/We2 partials, shfl-reduce, cross-half combine -> z;
//   fused heads (8 wave-slots; row = lane).
// ---------------------------------------------------------------------------
__global__ __launch_bounds__(512, 4)
void k1_fused(const float* __restrict__ x,
              const unsigned short* __restrict__ wp,
              const float* __restrict__ be1,
              const float* __restrict__ We2,
              const float* __restrict__ be2,
              const float* __restrict__ W1,
              const float* __restrict__ b1,
              const float* __restrict__ W2,
              const float* __restrict__ b2,
              const float* __restrict__ M,
              float* __restrict__ out,
              float* __restrict__ zout) {
  __shared__ char A0_[16384] __attribute__((aligned(16)));
  __shared__ char A1_[16384] __attribute__((aligned(16)));
  __shared__ char A2_[16384] __attribute__((aligned(16)));
  __shared__ char A3_[16384] __attribute__((aligned(16)));
  __shared__ float zpart2[64][2][2];   // [row][col-half][d]
  __shared__ float zsh[64][2];

  const int tid  = threadIdx.x;        // 0..511
  const int lane = tid & 63;
  const int wv   = tid >> 6;           // 0..7
  const int wr   = wv & 3;             // row-group (x16)
  const int wc   = wv >> 2;            // col-half (x64)
  const int l15  = lane & 15;
  const int kgrp = lane >> 4;          // 0..3
  const int blk  = blockIdx.x;

  // B: this wave's 8 fragments of chunk c at wp + wc*8192 + c*16384 + lane*16.
  // Base biased +4096: offsets (nt*2+ks)*1024 - 4096 = -4096..3072.
  const char* bwave = (const char*)wp + wc * 8192 + lane * 16 + 4096;

  f32x4 acc[4];
#pragma unroll
  for (int i = 0; i < 4; ++i) acc[i] = f32x4{0.f, 0.f, 0.f, 0.f};

  auto STAGE_A = [&](char* Ad, int c) {
    // slots s = tid, tid+512: row = s>>4, dest granule s&15,
    // source granule (s&15)^(row&7)
#pragma unroll
    for (int q = 0; q < 2; ++q) {
      int s = tid + q * 512;
      int row = s >> 4;
      int g = (s & 15) ^ (row & 7);
      const float* asrc = x + (size_t)(blk * BM + row) * KDIM + c * BK + g * 4;
      gload_lds16(asrc, Ad + s * 16);
    }
  };

  FragU bE[8], bO[8];
  auto LOADB = [&](FragU* B, int c) {
    const char* p = bwave + (size_t)c * 16384;
    GL16(B[0].u, p, "-4096");
    GL16(B[1].u, p, "-3072");
    GL16(B[2].u, p, "-2048");
    GL16(B[3].u, p, "-1024");
    GL16(B[4].u, p, "0");
    GL16(B[5].u, p, "1024");
    GL16(B[6].u, p, "2048");
    GL16(B[7].u, p, "3072");
  };

  auto COMPUTE = [&](const char* Ad, const FragU* B) {
    const int row = wr * 16 + l15;
    const char* abase = Ad + row * 256;
    const int rx = (row & 7) << 4;
    f32x4 A0 = *(const f32x4*)(abase + (((kgrp * 2 + 0) << 4) ^ rx));
    f32x4 A1 = *(const f32x4*)(abase + (((kgrp * 2 + 1) << 4) ^ rx));
    f32x4 A2 = *(const f32x4*)(abase + 128 + (((kgrp * 2 + 0) << 4) ^ rx));
    f32x4 A3 = *(const f32x4*)(abase + 128 + (((kgrp * 2 + 1) << 4) ^ rx));
    FragU a0, a1;
    a0.u = u32x4{cvt_pk_bf16(A0.x, A0.y), cvt_pk_bf16(A0.z, A0.w),
                 cvt_pk_bf16(A1.x, A1.y), cvt_pk_bf16(A1.z, A1.w)};
    a1.u = u32x4{cvt_pk_bf16(A2.x, A2.y), cvt_pk_bf16(A2.z, A2.w),
                 cvt_pk_bf16(A3.x, A3.y), cvt_pk_bf16(A3.z, A3.w)};
    acc[0] = __builtin_amdgcn_mfma_f32_16x16x32_bf16(a0.b, B[0].b, acc[0], 0, 0, 0);
    acc[0] = __builtin_amdgcn_mfma_f32_16x16x32_bf16(a1.b, B[1].b, acc[0], 0, 0, 0);
    acc[1] = __builtin_amdgcn_mfma_f32_16x16x32_bf16(a0.b, B[2].b, acc[1], 0, 0, 0);
    acc[1] = __builtin_amdgcn_mfma_f32_16x16x32_bf16(a1.b, B[3].b, acc[1], 0, 0, 0);
    acc[2] = __builtin_amdgcn_mfma_f32_16x16x32_bf16(a0.b, B[4].b, acc[2], 0, 0, 0);
    acc[2] = __builtin_amdgcn_mfma_f32_16x16x32_bf16(a1.b, B[5].b, acc[2], 0, 0, 0);
    acc[3] = __builtin_amdgcn_mfma_f32_16x16x32_bf16(a0.b, B[6].b, acc[3], 0, 0, 0);
    acc[3] = __builtin_amdgcn_mfma_f32_16x16x32_bf16(a1.b, B[7].b, acc[3], 0, 0, 0);
  };

// one phase: wait, barrier, compute chunk, then issue B(c+2) and A(c+3)
#define PH12(AB, BR, CB, AST, CA) do {                       \
    asm volatile("s_waitcnt vmcnt(12)" ::: "memory");        \
    SBAR();                                                  \
    __builtin_amdgcn_s_barrier();                            \
    COMPUTE(AB, BR);                                         \
    SBAR();                                                  \
    LOADB(BR, CB);                                           \
    STAGE_A(AST, CA);                                        \
  } while (0)

  // prologue (FIFO order A0,B0,A1,B1,A2 -> uniform vmcnt(12) from phase 0)
  STAGE_A(A0_, 0);
  LOADB(bE, 0);
  STAGE_A(A1_, 1);
  LOADB(bO, 1);
  STAGE_A(A2_, 2);

#pragma unroll 1
  for (int it = 0; it < 7; ++it) {       // phases 0..27
    const int c = it * 4;
    PH12(A0_, bE, c + 2, A3_, c + 3);
    PH12(A1_, bO, c + 3, A0_, c + 4);
    PH12(A2_, bE, c + 4, A1_, c + 5);
    PH12(A3_, bO, c + 5, A2_, c + 6);
  }
  // phase 28
  PH12(A0_, bE, 30, A3_, 31);
  // phase 29
  asm volatile("s_waitcnt vmcnt(12)" ::: "memory");
  SBAR();
  __builtin_amdgcn_s_barrier();
  COMPUTE(A1_, bO);
  SBAR();
  LOADB(bO, 31);
  // phase 30
  asm volatile("s_waitcnt vmcnt(10)" ::: "memory");
  SBAR();
  __builtin_amdgcn_s_barrier();
  COMPUTE(A2_, bE);
  // phase 31
  asm volatile("s_waitcnt vmcnt(0)" ::: "memory");
  SBAR();
  __builtin_amdgcn_s_barrier();
  COMPUTE(A3_, bO);
#undef PH12

  // ---- epilogue: +be1, relu, @We2 partials (this wave's 64 cols)
  float part[4][2];
#pragma unroll
  for (int j = 0; j < 4; ++j) { part[j][0] = 0.f; part[j][1] = 0.f; }
#pragma unroll
  for (int nt = 0; nt < 4; ++nt) {
    int col = (wc * 4 + nt) * 16 + l15;
    float bb = be1[col];
    float w0 = We2[col * 2 + 0];
    float w1 = We2[col * 2 + 1];
#pragma unroll
    for (int j = 0; j < 4; ++j) {
      float h = acc[nt][j] + bb;
      h = h > 0.f ? h : 0.f;
      part[j][0] = fmaf(h, w0, part[j][0]);
      part[j][1] = fmaf(h, w1, part[j][1]);
    }
  }
#pragma unroll
  for (int m = 1; m < 16; m <<= 1) {
#pragma unroll
    for (int j = 0; j < 4; ++j) {
      part[j][0] += __shfl_xor(part[j][0], m, 64);
      part[j][1] += __shfl_xor(part[j][1], m, 64);
    }
  }
  if (l15 == 0) {
#pragma unroll
    for (int j = 0; j < 4; ++j) {
      int rl = wr * 16 + kgrp * 4 + j;   // C row = (lane>>4)*4 + reg
      zpart2[rl][wc][0] = part[j][0];
      zpart2[rl][wc][1] = part[j][1];
    }
  }
  __syncthreads();
  if (tid < BM) {
    float s0 = zpart2[tid][0][0] + zpart2[tid][1][0] + be2[0];
    float s1 = zpart2[tid][0][1] + zpart2[tid][1][1] + be2[1];
    zsh[tid][0] = s0;
    zsh[tid][1] = s1;
    f32x2 zz = {s0, s1};
    *(f32x2*)(zout + (size_t)(blk * BM + tid) * 2) = zz;
  }
  __syncthreads();

  // ---- heads: row = lane, head slots per wave: wv, wv+8, (wv<4: wv+16)
  const int wvu = __builtin_amdgcn_readfirstlane(wv);
  float z0 = zsh[lane][0];
  float z1 = zsh[lane][1];
  float* orow = out + (size_t)(blk * BM + lane) * (VHEADS * PDIM);

  auto head = [&](int v) {
    const float* w1a = W1 + (size_t)(v * 2 + 0) * NDIM;
    const float* w1b = W1 + (size_t)(v * 2 + 1) * NDIM;
    const float* bb1 = b1 + (size_t)v * NDIM;
    const float* w2  = W2 + (size_t)v * NDIM * PDIM;

    float p[6] = {0.f, 0.f, 0.f, 0.f, 0.f, 0.f};
#pragma unroll 4
    for (int h = 0; h < NDIM; ++h) {
      float hv = fmaf(z0, w1a[h], fmaf(z1, w1b[h], bb1[h]));
      hv = hv > 0.f ? hv : 0.f;
#pragma unroll
      for (int j = 0; j < 6; ++j) p[j] = fmaf(hv, w2[h * 6 + j], p[j]);
    }
    float o[6];
#pragma unroll
    for (int j = 0; j < 6; ++j) {
      float t1 = fast_tanh(p[j] + b2[v * PDIM + j]);
      float lo = fmaf(z0, M[v * PDIM + j], z1 * M[VHEADS * PDIM + v * PDIM + j]);
      o[j] = fast_tanh(fmaf(0.15f, lo, t1));
    }
    float* op = orow + v * PDIM;
    f32x2 o01 = {o[0], o[1]};
    f32x2 o23 = {o[2], o[3]};
    f32x2 o45 = {o[4], o[5]};
    __builtin_nontemporal_store(o01, (f32x2*)(op + 0));
    __builtin_nontemporal_store(o23, (f32x2*)(op + 2));
    __builtin_nontemporal_store(o45, (f32x2*)(op + 4));
  };

  head(wvu);
  head(wvu + 8);
  if (wvu < 4) head(wvu + 16);
}

// ---------------------------------------------------------------------------
extern "C" void kernel_launch(void* const* d_in, const int* in_sizes, int n_in,
                              void* d_out, int out_size, void* d_ws, size_t ws_size,
                              hipStream_t stream) {
  const float* x   = (const float*)d_in[0];
  const float* We1 = (const float*)d_in[1];
  const float* be1 = (const float*)d_in[2];
  const float* We2 = (const float*)d_in[3];
  const float* be2 = (const float*)d_in[4];
  const float* W1  = (const float*)d_in[5];
  const float* b1  = (const float*)d_in[6];
  const float* W2  = (const float*)d_in[7];
  const float* b2  = (const float*)d_in[8];
  const float* lA  = (const float*)d_in[9];
  const float* lB  = (const float*)d_in[10];

  float* out  = (float*)d_out;
  float* zout = out + OUT_ELEMS;                       // second tuple output
  unsigned short* wsw = (unsigned short*)d_ws;         // 512 KB bf16 W pack
  float* wsM = (float*)((char*)d_ws + WS_W_BYTES);     // 240 floats

  hipLaunchKernelGGL(k0_pack, dim3(129), dim3(256), 0, stream,
                     We1, lA, lB, wsw, wsM);
  hipLaunchKernelGGL(k1_fused, dim3(BDIM / BM), dim3(512), 0, stream,
                     x, wsw, be1, We2, be2, W1, b1, W2, b2, wsM, out, zout);
}

// Round 21
// 96.020 us; speedup vs baseline: 1.6537x; 1.1799x over previous
//
#include <hip/hip_runtime.h>
#include <hip/hip_bf16.h>
#include <cstdint>
#include <cstddef>

// Problem constants
#define BDIM   32768
#define KDIM   2048
#define NDIM   128
#define VHEADS 20
#define PDIM   6
#define RLORA  10

#define BK      64
#define NCHUNK  (KDIM / BK)                 // 32
#define OUT_ELEMS   (BDIM * VHEADS * PDIM)  // 3932160
#define WS_W_BYTES  (KDIM * NDIM * 2)       // 524288

typedef __attribute__((ext_vector_type(8))) __bf16 bf16x8;
typedef __attribute__((ext_vector_type(4))) float f32x4;
typedef __attribute__((ext_vector_type(2))) float f32x2;
typedef __attribute__((ext_vector_type(4))) unsigned int u32x4;

union FragU { bf16x8 b; u32x4 u; };

__device__ __forceinline__ unsigned int cvt_pk_bf16(float lo, float hi) {
  unsigned int r;
  asm("v_cvt_pk_bf16_f32 %0, %1, %2" : "=v"(r) : "v"(lo), "v"(hi));
  return r;
}

__device__ __forceinline__ void gload_lds16(const void* g, void* l) {
  __builtin_amdgcn_global_load_lds(
      (const __attribute__((address_space(1))) void*)(g),
      (__attribute__((address_space(3))) void*)(l), 16, 0, 0);
}

__device__ __forceinline__ float fast_tanh(float x) {
  float ax = fabsf(x);
  float e  = __expf(-2.0f * ax);
  float t  = __fdividef(1.0f - e, 1.0f + e);
  return copysignf(t, x);
}

#define SBAR() __builtin_amdgcn_sched_barrier(0)

// ---------------------------------------------------------------------------
// k0: pack We1 f32[2048][128] -> bf16 in B-FRAGMENT-MAJOR order:
//   n = nt*16 + (lane&15), k = c*64 + ks*32 + (lane>>4)*8 + j.
//   Chunk c = 16 KB at c*16384; fragment (nt,ks) at (nt*2+ks)*1024 + lane*16.
// Also M = lora_A @ lora_B ([2][120]).
// ---------------------------------------------------------------------------
__global__ __launch_bounds__(256)
void k0_pack(const float* __restrict__ We1,
             const float* __restrict__ lA,
             const float* __restrict__ lB,
             unsigned short* __restrict__ wsw,
             float* __restrict__ wsM) {
  if (blockIdx.x == 128) {
    int t = threadIdx.x;
    if (t < 2 * VHEADS * PDIM) {
      int d  = t / (VHEADS * PDIM);
      int vp = t - d * (VHEADS * PDIM);
      float s = 0.f;
#pragma unroll
      for (int r = 0; r < RLORA; ++r)
        s = fmaf(lA[d * RLORA + r], lB[r * (VHEADS * PDIM) + vp], s);
      wsM[t] = s;  // layout [d][vp]
    }
    return;
  }
  int t    = blockIdx.x * 256 + threadIdx.x;  // 0..32767
  int lane = t & 63;
  int blk  = t >> 6;                          // 0..511
  int ks   = blk & 1;
  int nt   = (blk >> 1) & 7;
  int c    = blk >> 4;
  int n    = nt * 16 + (lane & 15);
  int kb   = c * 64 + ks * 32 + (lane >> 4) * 8;

  unsigned int u[4];
#pragma unroll
  for (int q = 0; q < 4; ++q) {
    float f0 = We1[(size_t)(kb + 2 * q + 0) * NDIM + n];
    float f1 = We1[(size_t)(kb + 2 * q + 1) * NDIM + n];
    __hip_bfloat16 h0 = __float2bfloat16(f0);
    __hip_bfloat16 h1 = __float2bfloat16(f1);
    u[q] = (unsigned int)*reinterpret_cast<unsigned short*>(&h0) |
           ((unsigned int)*reinterpret_cast<unsigned short*>(&h1) << 16);
  }
  *reinterpret_cast<u32x4*>(wsw + (size_t)t * 8) = u32x4{u[0], u[1], u[2], u[3]};
}

// ---------------------------------------------------------------------------
// k1: fused encoder + heads.  R14 (best-known-good): COUNTED-VMCNT pipeline.
//   512 blocks x 512 thr (8 waves: wr = wv&3 row-group x16, wc = wv>>2
//   col-half x64).  STATIC double-buffers (A0_/A1_/B0_/B1_ as distinct
//   __shared__ arrays, loop unrolled x2) so SIInsertWaitcnts can prove
//   ds_reads don't alias in-flight DMA -> counted s_waitcnt vmcnt(4)
//   sticks (4 loads/thread/chunk; next chunk's 4 stay in flight ACROSS
//   both raw s_barriers -- never drain to 0 in steady state).
//   A: f32 [64][64] via global_load_lds, linear dest, source granule
//      pre-XOR-swizzled (granule s of row r = global granule s^(r&7)).
//   B: fragment-packed bf16 (16 KB/chunk), linear dest.
//   Epilogue: be1/relu/We2 partials, shfl-reduce, cross-half combine -> z;
//   fused heads (8 wave-slots; row = lane).
// ---------------------------------------------------------------------------
__global__ __launch_bounds__(512, 4)
void k1_fused(const float* __restrict__ x,
              const unsigned short* __restrict__ wp,
              const float* __restrict__ be1,
              const float* __restrict__ We2,
              const float* __restrict__ be2,
              const float* __restrict__ W1,
              const float* __restrict__ b1,
              const float* __restrict__ W2,
              const float* __restrict__ b2,
              const float* __restrict__ M,
              float* __restrict__ out,
              float* __restrict__ zout) {
  __shared__ char A0_[16384] __attribute__((aligned(16)));
  __shared__ char A1_[16384] __attribute__((aligned(16)));
  __shared__ char B0_[16384] __attribute__((aligned(16)));
  __shared__ char B1_[16384] __attribute__((aligned(16)));
  __shared__ float zpart2[64][2][2];   // [row][col-half][d]
  __shared__ float zsh[64][2];

  const int tid  = threadIdx.x;        // 0..511
  const int lane = tid & 63;
  const int wv   = tid >> 6;           // 0..7
  const int wr   = wv & 3;             // row-group (x16)
  const int wc   = wv >> 2;            // col-half (x64)
  const int l15  = lane & 15;
  const int kgrp = lane >> 4;          // 0..3
  const int blk  = blockIdx.x;

  f32x4 acc[4];
#pragma unroll
  for (int i = 0; i < 4; ++i) acc[i] = f32x4{0.f, 0.f, 0.f, 0.f};

  auto STAGE = [&](char* Ad, char* Bd, int c) {
    // A: slots s = tid, tid+512 (row = s>>4, dest granule s&15,
    //    source granule (s&15)^(row&7))
#pragma unroll
    for (int q = 0; q < 2; ++q) {
      int s = tid + q * 512;
      int row = s >> 4;
      int g = (s & 15) ^ (row & 7);
      const float* asrc = x + (size_t)(blk * 64 + row) * KDIM + c * BK + g * 4;
      gload_lds16(asrc, Ad + s * 16);
    }
    // B: linear copy of the 16 KB chunk
#pragma unroll
    for (int q = 0; q < 2; ++q) {
      gload_lds16((const char*)wp + (size_t)c * 16384 + q * 8192 + tid * 16,
                  Bd + q * 8192 + tid * 16);
    }
  };

  auto COMPUTE = [&](const char* Ad, const char* Bd) {
    const int row = wr * 16 + l15;
    const char* abase = Ad + row * 256;
    const int rx = (row & 7) << 4;
    f32x4 A0 = *(const f32x4*)(abase + (((kgrp * 2 + 0) << 4) ^ rx));
    f32x4 A1 = *(const f32x4*)(abase + (((kgrp * 2 + 1) << 4) ^ rx));
    f32x4 A2 = *(const f32x4*)(abase + 128 + (((kgrp * 2 + 0) << 4) ^ rx));
    f32x4 A3 = *(const f32x4*)(abase + 128 + (((kgrp * 2 + 1) << 4) ^ rx));
    FragU a0, a1;
    a0.u = u32x4{cvt_pk_bf16(A0.x, A0.y), cvt_pk_bf16(A0.z, A0.w),
                 cvt_pk_bf16(A1.x, A1.y), cvt_pk_bf16(A1.z, A1.w)};
    a1.u = u32x4{cvt_pk_bf16(A2.x, A2.y), cvt_pk_bf16(A2.z, A2.w),
                 cvt_pk_bf16(A3.x, A3.y), cvt_pk_bf16(A3.z, A3.w)};
    const char* bbase = Bd + lane * 16;
#pragma unroll
    for (int nt = 0; nt < 4; ++nt) {
      FragU b0, b1;
      b0.u = *(const u32x4*)(bbase + ((wc * 4 + nt) * 2 + 0) * 1024);
      b1.u = *(const u32x4*)(bbase + ((wc * 4 + nt) * 2 + 1) * 1024);
      acc[nt] = __builtin_amdgcn_mfma_f32_16x16x32_bf16(a0.b, b0.b, acc[nt], 0, 0, 0);
      acc[nt] = __builtin_amdgcn_mfma_f32_16x16x32_bf16(a1.b, b1.b, acc[nt], 0, 0, 0);
    }
  };

  // prologue: chunks 0,1 in flight (8 loads/thread)
  STAGE(A0_, B0_, 0);
  STAGE(A1_, B1_, 1);

#pragma unroll 1
  for (int cc = 0; cc < NCHUNK / 2 - 1; ++cc) {   // computes 2cc, 2cc+1
    asm volatile("s_waitcnt vmcnt(4)" ::: "memory");   // chunk 2cc landed
    SBAR();
    __builtin_amdgcn_s_barrier();
    COMPUTE(A0_, B0_);
    __builtin_amdgcn_s_barrier();
    SBAR();
    STAGE(A0_, B0_, 2 * cc + 2);                       // back to 8 in flight
    asm volatile("s_waitcnt vmcnt(4)" ::: "memory");   // chunk 2cc+1 landed
    SBAR();
    __builtin_amdgcn_s_barrier();
    COMPUTE(A1_, B1_);
    __builtin_amdgcn_s_barrier();
    SBAR();
    STAGE(A1_, B1_, 2 * cc + 3);
  }
  // tail: chunks 30, 31 (no further staging)
  asm volatile("s_waitcnt vmcnt(4)" ::: "memory");
  SBAR();
  __builtin_amdgcn_s_barrier();
  COMPUTE(A0_, B0_);
  asm volatile("s_waitcnt vmcnt(0)" ::: "memory");
  SBAR();
  __builtin_amdgcn_s_barrier();
  COMPUTE(A1_, B1_);

  // ---- epilogue: +be1, relu, @We2 partials (this wave's 64 cols)
  float part[4][2];
#pragma unroll
  for (int j = 0; j < 4; ++j) { part[j][0] = 0.f; part[j][1] = 0.f; }
#pragma unroll
  for (int nt = 0; nt < 4; ++nt) {
    int col = (wc * 4 + nt) * 16 + l15;
    float bb = be1[col];
    float w0 = We2[col * 2 + 0];
    float w1 = We2[col * 2 + 1];
#pragma unroll
    for (int j = 0; j < 4; ++j) {
      float h = acc[nt][j] + bb;
      h = h > 0.f ? h : 0.f;
      part[j][0] = fmaf(h, w0, part[j][0]);
      part[j][1] = fmaf(h, w1, part[j][1]);
    }
  }
#pragma unroll
  for (int m = 1; m < 16; m <<= 1) {
#pragma unroll
    for (int j = 0; j < 4; ++j) {
      part[j][0] += __shfl_xor(part[j][0], m, 64);
      part[j][1] += __shfl_xor(part[j][1], m, 64);
    }
  }
  if (l15 == 0) {
#pragma unroll
    for (int j = 0; j < 4; ++j) {
      int rl = wr * 16 + kgrp * 4 + j;   // C row = (lane>>4)*4 + reg
      zpart2[rl][wc][0] = part[j][0];
      zpart2[rl][wc][1] = part[j][1];
    }
  }
  __syncthreads();
  if (tid < 64) {
    float s0 = zpart2[tid][0][0] + zpart2[tid][1][0] + be2[0];
    float s1 = zpart2[tid][0][1] + zpart2[tid][1][1] + be2[1];
    zsh[tid][0] = s0;
    zsh[tid][1] = s1;
    f32x2 zz = {s0, s1};
    *(f32x2*)(zout + (size_t)(blk * 64 + tid) * 2) = zz;
  }
  __syncthreads();

  // ---- heads: row = lane, head slots per wave: wv, wv+8, (wv<4: wv+16)
  const int wvu = __builtin_amdgcn_readfirstlane(wv);
  float z0 = zsh[lane][0];
  float z1 = zsh[lane][1];
  float* orow = out + (size_t)(blk * 64 + lane) * (VHEADS * PDIM);

  auto head = [&](int v) {
    const float* w1a = W1 + (size_t)(v * 2 + 0) * NDIM;
    const float* w1b = W1 + (size_t)(v * 2 + 1) * NDIM;
    const float* bb1 = b1 + (size_t)v * NDIM;
    const float* w2  = W2 + (size_t)v * NDIM * PDIM;

    float p[6] = {0.f, 0.f, 0.f, 0.f, 0.f, 0.f};
#pragma unroll 4
    for (int h = 0; h < NDIM; ++h) {
      float hv = fmaf(z0, w1a[h], fmaf(z1, w1b[h], bb1[h]));
      hv = hv > 0.f ? hv : 0.f;
#pragma unroll
      for (int j = 0; j < 6; ++j) p[j] = fmaf(hv, w2[h * 6 + j], p[j]);
    }
    float o[6];
#pragma unroll
    for (int j = 0; j < 6; ++j) {
      float t1 = fast_tanh(p[j] + b2[v * PDIM + j]);
      float lo = fmaf(z0, M[v * PDIM + j], z1 * M[VHEADS * PDIM + v * PDIM + j]);
      o[j] = fast_tanh(fmaf(0.15f, lo, t1));
    }
    float* op = orow + v * PDIM;
    f32x2 o01 = {o[0], o[1]};
    f32x2 o23 = {o[2], o[3]};
    f32x2 o45 = {o[4], o[5]};
    __builtin_nontemporal_store(o01, (f32x2*)(op + 0));
    __builtin_nontemporal_store(o23, (f32x2*)(op + 2));
    __builtin_nontemporal_store(o45, (f32x2*)(op + 4));
  };

  head(wvu);
  head(wvu + 8);
  if (wvu < 4) head(wvu + 16);
}

// ---------------------------------------------------------------------------
extern "C" void kernel_launch(void* const* d_in, const int* in_sizes, int n_in,
                              void* d_out, int out_size, void* d_ws, size_t ws_size,
                              hipStream_t stream) {
  const float* x   = (const float*)d_in[0];
  const float* We1 = (const float*)d_in[1];
  const float* be1 = (const float*)d_in[2];
  const float* We2 = (const float*)d_in[3];
  const float* be2 = (const float*)d_in[4];
  const float* W1  = (const float*)d_in[5];
  const float* b1  = (const float*)d_in[6];
  const float* W2  = (const float*)d_in[7];
  const float* b2  = (const float*)d_in[8];
  const float* lA  = (const float*)d_in[9];
  const float* lB  = (const float*)d_in[10];

  float* out  = (float*)d_out;
  float* zout = out + OUT_ELEMS;                       // second tuple output
  unsigned short* wsw = (unsigned short*)d_ws;         // 512 KB bf16 W pack
  float* wsM = (float*)((char*)d_ws + WS_W_BYTES);     // 240 floats

  hipLaunchKernelGGL(k0_pack, dim3(129), dim3(256), 0, stream,
                     We1, lA, lB, wsw, wsM);
  hipLaunchKernelGGL(k1_fused, dim3(BDIM / 64), dim3(512), 0, stream,
                     x, wsw, be1, We2, be2, W1, b1, W2, b2, wsM, out, zout);
}